// Round 14
// baseline (83.188 us; speedup 1.0000x reference)
//
#include <hip/hip_runtime.h>
#include <hip/hip_bf16.h>
#include <math.h>

#define LL 1024
#define BB 4
#define HH 8
#define EE 64
#define CC (HH*EE)  // 512

typedef __attribute__((ext_vector_type(4))) float f32x4;
typedef __attribute__((ext_vector_type(8))) short bf16x8;
typedef __attribute__((ext_vector_type(4))) short bf16x4;

__device__ __forceinline__ unsigned short f2bf(float x) {
    unsigned u = __float_as_uint(x);
    u += 0x7FFFu + ((u >> 16) & 1u);   // round-to-nearest-even
    return (unsigned short)(u >> 16);
}

// global_load_lds 16B: per-lane global src, wave-uniform LDS dest (+lane*16 by HW)
__device__ __forceinline__ void dma16(const void* g, void* l) {
    typedef const __attribute__((address_space(1))) unsigned int* gup;
    typedef __attribute__((address_space(3))) unsigned int* lup;
    gup gp = (gup)(unsigned long long)g;
    lup lp = (lup)(unsigned int)(unsigned long long)l;
    __builtin_amdgcn_global_load_lds(gp, lp, 16, 0, 0);
}

// ---------------- kernel 1 (merged): scan | prepA | prepX ----------------
__global__ __launch_bounds__(1024) void k_pre(const float* __restrict__ hurst,
                                              const float* __restrict__ tau,
                                              const float* __restrict__ q,
                                              float* __restrict__ psi,
                                              float* __restrict__ taut,
                                              unsigned short* __restrict__ Agh,
                                              unsigned short* __restrict__ Agl,
                                              unsigned short* __restrict__ Xh,
                                              unsigned short* __restrict__ Xl) {
    __shared__ float sh[1024];
    int bid = blockIdx.x;
    int t = threadIdx.x;

    if (bid < 32) {
        int bh = bid;
        int b = bh >> 3, h = bh & 7;
        int l = t;
        float hu = hurst[((size_t)b * LL + l) * HH + h];
        float ht = 1.f / (1.f + expf(-hu)) * 0.99f + 0.01f;
        sh[l] = expf(2.0f * ht);
        __syncthreads();
        for (int off = 1; off < LL; off <<= 1) {
            float tmp = (l >= off) ? sh[l - off] : 0.f;
            __syncthreads();
            sh[l] += tmp;
            __syncthreads();
        }
        psi[((size_t)b * HH + h) * LL + l] = sh[l];
        float tv = tau[((size_t)b * LL + l) * HH + h];
        taut[((size_t)b * HH + h) * LL + l] = 1.f / (1.f + expf(-tv)) * 0.9f + 0.1f;
    } else if (bid < 288) {
        {
            int d = t;
            float vv = 0.f;
            if (d & 1) {
                float a = 3.14159265358979323846f * (float)d / (float)LL;
                vv = (2.0f / (float)LL) * (cosf(a) / sinf(a));
            }
            sh[d] = vv;
        }
        __syncthreads();
        int bb = bid - 32;               // im*16 + kt
        int im = bb >> 4, kt = bb & 15;
        if (t < 512) {
            int row = t >> 3, gr = t & 7;
            int i = im * 64 + row;
            bf16x8 hv, lv;
            #pragma unroll
            for (int j = 0; j < 8; ++j) {
                int kl = gr * 8 + j;
                float gg = sh[(i - kt * 64 - kl) & 1023];
                unsigned short hh = f2bf(gg);
                hv[j] = (short)hh;
                lv[j] = (short)f2bf(gg - __uint_as_float(((unsigned)hh) << 16));
            }
            size_t base = (size_t)bb * 4096;
            int pos = gr ^ (row & 7);
            *(bf16x8*)&Agh[base + row * 64 + pos * 8] = hv;
            *(bf16x8*)&Agl[base + row * 64 + pos * 8] = lv;
        }
    } else {
        int bb = bid - 288;              // kt*16 + np
        int kt = bb >> 4, np = bb & 15;
        int bq = np >> 2;
        const float* qb = q + (size_t)bq * LL * CC;
        size_t base = (size_t)bb * 8192;
        int gid = t;
        int nl = gid & 15, nb = (gid >> 4) & 7, kg = gid >> 7;
        int e_n = np * 128 + nb * 16 + nl;
        int cy = (e_n >> 6) & 7;
        int e = e_n & 63;
        bf16x8 hv, lv;
        #pragma unroll
        for (int j = 0; j < 8; ++j) {
            int k = kt * 64 + kg * 8 + j;
            int l = ((k & 127) << 3) | cy;
            int h2 = k >> 7;
            float val = qb[l * 512 + h2 * 64 + e];
            unsigned short hh = f2bf(val);
            hv[j] = (short)hh;
            lv[j] = (short)f2bf(val - __uint_as_float(((unsigned)hh) << 16));
        }
        *(bf16x8*)&Xh[base + (size_t)gid * 8] = hv;
        *(bf16x8*)&Xl[base + (size_t)gid * 8] = lv;
    }
}

// ---------------- kernel 2: MFMA Hilbert conv — counted-vmcnt loop ----------
__global__ __launch_bounds__(256) void k_hilb(const float* __restrict__ q,
                                              const unsigned short* __restrict__ Agh,
                                              const unsigned short* __restrict__ Agl,
                                              const unsigned short* __restrict__ Xh,
                                              const unsigned short* __restrict__ Xl,
                                              float* __restrict__ part_s,
                                              float* __restrict__ part_c) {
    __shared__ __align__(16) char smemB[98304];

    int t = threadIdx.x, lid = t & 63, wv = t >> 6;
    int m16 = lid & 15, g = lid >> 4;
    int wi = wv >> 1, wn = wv & 1;

    int bid = blockIdx.x;
    int xcd = bid & 7, o = bid >> 3;
    int im = ((xcd >> 2) << 3) + (o & 7);
    int np = ((xcd & 3) << 2) + (o >> 3);
    int i0 = im * 64, n0 = np * 128;
    int bq = np >> 2, quad = np & 3;
    const float* qb = q + (size_t)bq * LL * CC;

    const char* Ah_g = (const char*)Agh + (size_t)im * 16 * 8192;
    const char* Al_g = (const char*)Agl + (size_t)im * 16 * 8192;
    const char* Xh_g = (const char*)Xh;
    const char* Xl_g = (const char*)Xl;

#define AHOFF(bf) ((bf) * 49152)
#define ALOFF(bf) ((bf) * 49152 + 8192)
#define XHOFF(bf) ((bf) * 49152 + 16384)
#define XLOFF(bf) ((bf) * 49152 + 32768)
#define STAGE(bf, kt)                                                          \
    {                                                                          \
        size_t xb = ((size_t)(kt) * 16 + np) * 16384;                          \
        _Pragma("unroll")                                                      \
        for (int c = 0; c < 2; ++c) {                                          \
            int ch = wv + 4 * c;                                               \
            dma16(Ah_g + (kt) * 8192 + ch * 1024 + lid * 16,                   \
                  smemB + AHOFF(bf) + ch * 1024);                              \
            dma16(Al_g + (kt) * 8192 + ch * 1024 + lid * 16,                   \
                  smemB + ALOFF(bf) + ch * 1024);                              \
        }                                                                      \
        _Pragma("unroll")                                                      \
        for (int c = 0; c < 4; ++c) {                                          \
            int ch = wv + 4 * c;                                               \
            dma16(Xh_g + xb + ch * 1024 + lid * 16,                            \
                  smemB + XHOFF(bf) + ch * 1024);                              \
            dma16(Xl_g + xb + ch * 1024 + lid * 16,                            \
                  smemB + XLOFF(bf) + ch * 1024);                              \
        }                                                                      \
    }

    STAGE(0, 0);
    __syncthreads();   // prologue: full drain of buf0

    f32x4 acc[2][4];
    #pragma unroll
    for (int mf = 0; mf < 2; ++mf)
        #pragma unroll
        for (int nf = 0; nf < 4; ++nf) acc[mf][nf] = (f32x4){0.f, 0.f, 0.f, 0.f};

    int cur = 0;
    for (int kt = 0; kt < 16; ++kt) {
        // T4: issue next batch, wait only for cur's batch (12/wave)
        if (kt < 15) {
            STAGE(cur ^ 1, kt + 1);
            asm volatile("s_waitcnt vmcnt(12)" ::: "memory");
        } else {
            asm volatile("s_waitcnt vmcnt(0)" ::: "memory");
        }
        __builtin_amdgcn_sched_barrier(0);
        __builtin_amdgcn_s_barrier();
        asm volatile("" ::: "memory");

        const unsigned short* AhL = (const unsigned short*)(smemB + AHOFF(cur));
        const unsigned short* AlL = (const unsigned short*)(smemB + ALOFF(cur));
        const unsigned short* XhL = (const unsigned short*)(smemB + XHOFF(cur));
        const unsigned short* XlL = (const unsigned short*)(smemB + XLOFF(cur));

        __builtin_amdgcn_s_setprio(1);
        #pragma unroll
        for (int s = 0; s < 2; ++s) {
            bf16x8 Ahf[2], Alf[2];
            #pragma unroll
            for (int mf = 0; mf < 2; ++mf) {
                int row = wi * 32 + 16 * mf + m16;
                int pos = (s * 4 + g) ^ (m16 & 7);
                Ahf[mf] = *(bf16x8*)&AhL[row * 64 + pos * 8];
                Alf[mf] = *(bf16x8*)&AlL[row * 64 + pos * 8];
            }
            #pragma unroll
            for (int nf = 0; nf < 4; ++nf) {
                int nb = wn * 4 + nf;
                int goff = (((s * 4 + g) * 8 + nb) * 16 + m16) * 8;
                bf16x8 Bh = *(bf16x8*)&XhL[goff];
                bf16x8 Bl = *(bf16x8*)&XlL[goff];
                #pragma unroll
                for (int mf = 0; mf < 2; ++mf) {
                    acc[mf][nf] = __builtin_amdgcn_mfma_f32_16x16x32_bf16(Ahf[mf], Bh, acc[mf][nf], 0, 0, 0);
                    acc[mf][nf] = __builtin_amdgcn_mfma_f32_16x16x32_bf16(Ahf[mf], Bl, acc[mf][nf], 0, 0, 0);
                    acc[mf][nf] = __builtin_amdgcn_mfma_f32_16x16x32_bf16(Alf[mf], Bh, acc[mf][nf], 0, 0, 0);
                }
            }
        }
        __builtin_amdgcn_s_setprio(0);

        asm volatile("" ::: "memory");
        __builtin_amdgcn_s_barrier();   // all waves done reading cur
        cur ^= 1;
    }

    // ---- epilogue: theta partials ----
    float svacc[2][4], cvacc[2][4];
    #pragma unroll
    for (int mf = 0; mf < 2; ++mf)
        #pragma unroll
        for (int r = 0; r < 4; ++r) { svacc[mf][r] = 0.f; cvacc[mf][r] = 0.f; }

    #pragma unroll
    for (int mf = 0; mf < 2; ++mf) {
        #pragma unroll
        for (int nf = 0; nf < 4; ++nf) {
            #pragma unroll
            for (int r = 0; r < 4; ++r) {
                float iv = acc[mf][nf][r];
                int ig = i0 + wi * 32 + 16 * mf + 4 * g + r;
                int ng = n0 + wn * 64 + 16 * nf + m16;
                int cc2 = ng & 511;
                int cy = cc2 >> 6, e = cc2 & 63;
                int l = ((ig & 127) << 3) | cy;
                int h2 = ig >> 7;
                float re = qb[l * 512 + h2 * 64 + e];
                float rr = sqrtf(re * re + iv * iv);
                float sv, cv;
                if (rr > 0.f) { sv = iv / rr; cv = re / rr; }
                else { sv = 0.f; cv = 1.f; }
                svacc[mf][r] += sv;
                cvacc[mf][r] += cv;
            }
        }
    }
    __syncthreads();   // smemB reuse
    float* psv = (float*)smemB;
    float* pcv = (float*)(smemB + 512);
    #pragma unroll
    for (int mf = 0; mf < 2; ++mf) {
        #pragma unroll
        for (int r = 0; r < 4; ++r) {
            float s = svacc[mf][r], c = cvacc[mf][r];
            s += __shfl_xor(s, 1); s += __shfl_xor(s, 2);
            s += __shfl_xor(s, 4); s += __shfl_xor(s, 8);
            c += __shfl_xor(c, 1); c += __shfl_xor(c, 2);
            c += __shfl_xor(c, 4); c += __shfl_xor(c, 8);
            if (m16 == 0) {
                psv[wv * 32 + 16 * mf + 4 * g + r] = s;
                pcv[wv * 32 + 16 * mf + 4 * g + r] = c;
            }
        }
    }
    __syncthreads();
    if (t < 64) {
        int wg = (t >> 5) * 2;
        float s = psv[wg * 32 + (t & 31)] + psv[(wg + 1) * 32 + (t & 31)];
        float c = pcv[wg * 32 + (t & 31)] + pcv[(wg + 1) * 32 + (t & 31)];
        size_t oidx = ((size_t)bq * 1024 + (i0 + t)) * 4 + quad;
        part_s[oidx] = s;
        part_c[oidx] = c;
    }
#undef AHOFF
#undef ALOFF
#undef XHOFF
#undef XLOFF
#undef STAGE
}

// ---------------- kernel 3: prep — Q/K/V bf16 layouts, pcs (+theta inline) ----
__global__ __launch_bounds__(256) void k_prep(const float* __restrict__ q,
                                              const float* __restrict__ k,
                                              const float* __restrict__ v,
                                              const float* __restrict__ psi,
                                              const float* __restrict__ taut,
                                              const float* __restrict__ part_s,
                                              const float* __restrict__ part_c,
                                              unsigned short* __restrict__ Qp,
                                              unsigned short* __restrict__ Kp,
                                              unsigned short* __restrict__ Vp,
                                              float* __restrict__ pcs) {
    __shared__ unsigned short vt[4096];
    int t = threadIdx.x;
    int blk = blockIdx.x;
    int tile = blk & 15;
    int bh = blk >> 4;
    int h = bh & 7, b = bh >> 3;
    int l0 = tile * 64;

    const float* qg = q + ((size_t)(b * LL + l0) * CC + (size_t)h * EE);
    const float* kg = k + ((size_t)(b * LL + l0) * CC + (size_t)h * EE);
    const float* vg = v + ((size_t)(b * LL + l0) * CC + (size_t)h * EE);
    unsigned short* Qo = Qp + ((size_t)bh * LL + l0) * 64;
    unsigned short* Ko = Kp + ((size_t)bh * LL + l0) * 64;
    unsigned short* Vo = Vp + ((size_t)bh * 16 + tile) * 4096;

    const float QS = 0.18033688011112042f;  // 0.125 * log2(e)

    #pragma unroll
    for (int it = 0; it < 2; ++it) {
        int x = it * 256 + t;
        int row = x >> 3, gr = x & 7;
        int pos = (gr ^ (row & 7)) * 8;
        const float* src = qg + (size_t)row * CC + gr * 8;
        float4 a4 = *(const float4*)src;
        float4 b4 = *(const float4*)(src + 4);
        bf16x8 o;
        o[0] = (short)f2bf(QS * a4.x); o[1] = (short)f2bf(QS * a4.y);
        o[2] = (short)f2bf(QS * a4.z); o[3] = (short)f2bf(QS * a4.w);
        o[4] = (short)f2bf(QS * b4.x); o[5] = (short)f2bf(QS * b4.y);
        o[6] = (short)f2bf(QS * b4.z); o[7] = (short)f2bf(QS * b4.w);
        *(bf16x8*)&Qo[row * 64 + pos] = o;
        src = kg + (size_t)row * CC + gr * 8;
        a4 = *(const float4*)src;
        b4 = *(const float4*)(src + 4);
        o[0] = (short)f2bf(a4.x); o[1] = (short)f2bf(a4.y);
        o[2] = (short)f2bf(a4.z); o[3] = (short)f2bf(a4.w);
        o[4] = (short)f2bf(b4.x); o[5] = (short)f2bf(b4.y);
        o[6] = (short)f2bf(b4.z); o[7] = (short)f2bf(b4.w);
        *(bf16x8*)&Ko[row * 64 + pos] = o;
    }

    #pragma unroll
    for (int it = 0; it < 4; ++it) {
        int x = it * 256 + t;
        int s = x >> 4, i = x & 15;
        float4 a4 = *(const float4*)(vg + (size_t)s * CC + i * 4);
        int c = s >> 5, g4 = (s >> 2) & 3;
        int jj = ((s >> 4) & 1) * 4 + (s & 3);
        float vals[4] = {a4.x, a4.y, a4.z, a4.w};
        #pragma unroll
        for (int j2 = 0; j2 < 4; ++j2) {
            int e = i * 4 + j2;
            int ef = e >> 4, m16 = e & 15;
            vt[((((ef * 2 + c) * 4 + g4) * 16 + m16) * 8) + jj] = f2bf(vals[j2]);
        }
    }
    __syncthreads();
    #pragma unroll
    for (int it = 0; it < 2; ++it) {
        int x = it * 256 + t;
        *(bf16x8*)&Vo[x * 8] = *(bf16x8*)&vt[x * 8];
    }

    if (t < 64) {
        int l = l0 + t;
        float ss = 0.f, cc2 = 0.f;
        size_t pbase = ((size_t)b * 1024 + l) * 4;
        #pragma unroll
        for (int qd = 0; qd < 4; ++qd) {
            ss += part_s[pbase + qd];
            cc2 += part_c[pbase + qd];
        }
        float r2 = ss * ss + cc2 * cc2;
        float cth = 1.f, sth = 0.f;
        if (r2 > 0.f) {
            float rn = rsqrtf(r2);
            cth = cc2 * rn; sth = ss * rn;
        }
        float ta = taut[(size_t)bh * LL + l];
        float4 o;
        o.x = psi[(size_t)bh * LL + l] * 0.8493218003f;   // sqrt(log2e/2)
        o.y = cth;
        o.z = sth;
        o.w = 0.3606737602f / (ta * ta);                  // log2e/(4 tau^2)
        *(float4*)&pcs[((size_t)bh * LL + l) * 4] = o;
    }
}

// ---------------- kernel 4: MFMA flash attn — 8 waves (4 qg x 2 sg), reg-Q ----
// sg splits each 64-s tile in half; sg == PV chunk index c, so P-frag packing
// is direct. Single shared K/V dbuf. Cross-sg combine in epilogue via LDS.
__global__ __launch_bounds__(512, 4) void k_attn(const unsigned short* __restrict__ Qp,
                                                 const unsigned short* __restrict__ Kp,
                                                 const unsigned short* __restrict__ Vp,
                                                 const float* __restrict__ pcs,
                                                 float* __restrict__ out) {
    // k dbuf 0..16383 | v dbuf 16384..32767 | pcs dbuf 32768..34815; epi scratch 35840
    __shared__ __align__(16) char smemB[35840];

    int t = threadIdx.x;
    int lid = t & 63;
    int wv = t >> 6;          // 0..7
    int qg = wv & 3, sg = wv >> 2;
    int m16 = lid & 15;
    int g = lid >> 4;

    int bid = blockIdx.x;
    int blk = (bid & 7) * 64 + (bid >> 3);
    int qt = blk & 15;
    int bh = blk >> 4;
    int h = bh & 7, b = bh >> 3;
    int l0 = qt * 64;

    const char* Qg = (const char*)(Qp + ((size_t)bh * LL + l0) * 64);
    const char* Kg = (const char*)(Kp + (size_t)bh * LL * 64);
    const char* Vg = (const char*)(Vp + (size_t)bh * LL * 64);
    const float* pcsg = pcs + (size_t)bh * LL * 4;

    int qrow = qg * 16 + m16;
    float4 myq = *(const float4*)&pcsg[(size_t)(l0 + qrow) * 4];
    float psiq = myq.x, cq = myq.y, sq = myq.z;
    float wgt = myq.w, nwgt = -myq.w;

#define KOFF(bf) ((bf) * 8192)
#define VOFF(bf) (16384 + (bf) * 8192)
#define POFF(bf) (32768 + (bf) * 1024)
// 3 dma16 per wave: 1 K chunk, 1 V chunk, pcs (all waves dup -> uniform count)
#define STAGE(bf, tile)                                                        \
    {                                                                          \
        const char* kb8 = Kg + (tile) * 8192;                                  \
        const char* vb8 = Vg + (tile) * 8192;                                  \
        dma16(kb8 + wv * 1024 + lid * 16, smemB + KOFF(bf) + wv * 1024);       \
        dma16(vb8 + wv * 1024 + lid * 16, smemB + VOFF(bf) + wv * 1024);       \
        dma16((const char*)pcsg + (tile) * 1024 + lid * 16, smemB + POFF(bf)); \
    }

    // Q B-frags straight from global (Qp layout == frag layout)
    bf16x8 qf[2];
    #pragma unroll
    for (int ec = 0; ec < 2; ++ec) {
        int pos = (4 * ec + g) ^ (m16 & 7);
        qf[ec] = *(const bf16x8*)(Qg + ((qg * 16 + m16) * 64 + pos * 8) * 2);
    }
    STAGE(0, 0);
    __syncthreads();   // prologue: full drain (Q regs + buf0)

    f32x4 accS[4], accP[4];
    #pragma unroll
    for (int f = 0; f < 4; ++f) {
        accS[f] = (f32x4){0.f, 0.f, 0.f, 0.f};
        accP[f] = (f32x4){0.f, 0.f, 0.f, 0.f};
    }
    float ssel = 0.f, spgl = 0.f;
    int cur = 0;

    for (int tile = 0; tile < 16; ++tile) {
        if (tile < 15) {
            STAGE(cur ^ 1, tile + 1);
            asm volatile("s_waitcnt vmcnt(3)" ::: "memory");
        } else {
            asm volatile("s_waitcnt vmcnt(0)" ::: "memory");
        }
        __builtin_amdgcn_sched_barrier(0);
        __builtin_amdgcn_s_barrier();
        asm volatile("" ::: "memory");

        const unsigned short* kbuf = (const unsigned short*)(smemB + KOFF(cur));
        const unsigned short* vbuf = (const unsigned short*)(smemB + VOFF(cur));
        const float* pcb = (const float*)(smemB + POFF(cur));

        // ---- S^T over this wave's s-half: f in {0,1}, s = sg*32+16f+4g+r ----
        f32x4 st[2];
        st[0] = (f32x4){0.f, 0.f, 0.f, 0.f};
        st[1] = (f32x4){0.f, 0.f, 0.f, 0.f};
        __builtin_amdgcn_s_setprio(1);
        #pragma unroll
        for (int ec = 0; ec < 2; ++ec) {
            int pos = (4 * ec + g) ^ (m16 & 7);
            #pragma unroll
            for (int f = 0; f < 2; ++f) {
                bf16x8 ka = *(bf16x8*)&kbuf[(sg * 32 + 16 * f + m16) * 64 + pos * 8];
                st[f] = __builtin_amdgcn_mfma_f32_16x16x32_bf16(ka, qf[ec], st[f], 0, 0, 0);
            }
        }
        __builtin_amdgcn_s_setprio(0);

        // ---- softmax (max=0) + fused prior*gate for 8 elems ----
        float psum = 0.f;
        float ps_[8], pg_[8];
        #pragma unroll
        for (int f = 0; f < 2; ++f) {
            #pragma unroll
            for (int r = 0; r < 4; ++r) {
                float4 pc4 = *(const float4*)&pcb[(sg * 32 + 16 * f + 4 * g + r) * 4];
                float p = exp2f(st[f][r]);
                psum += p;
                float d = psiq - pc4.x;
                float cd = fmaf(cq, pc4.y, sq * pc4.z);
                float arg = fmaf(-d, d, fmaf(wgt, cd, nwgt));  // w*cd - w - d^2
                float pgv = exp2f(arg);
                spgl += pgv;
                ps_[f * 4 + r] = p;
                pg_[f * 4 + r] = pgv;
            }
        }
        ssel += psum;

        union PK4 { unsigned w[4]; bf16x8 v; } SS, GG;
        #pragma unroll
        for (int i2 = 0; i2 < 4; ++i2) {
            __hip_bfloat162 hs = __float22bfloat162_rn(
                make_float2(ps_[2 * i2], ps_[2 * i2 + 1]));
            __hip_bfloat162 hg = __float22bfloat162_rn(
                make_float2(pg_[2 * i2], pg_[2 * i2 + 1]));
            unsigned ws, wg2;
            __builtin_memcpy(&ws, &hs, 4);
            __builtin_memcpy(&wg2, &hg, 4);
            SS.w[i2] = ws;
            GG.w[i2] = wg2;
        }

        // ---- PV: this wave's chunk c = sg ----
        __builtin_amdgcn_s_setprio(1);
        #pragma unroll
        for (int ef = 0; ef < 4; ++ef) {
            bf16x8 vb = *(bf16x8*)&vbuf[(((ef * 2 + sg) * 4 + g) * 16 + m16) * 8];
            accS[ef] = __builtin_amdgcn_mfma_f32_16x16x32_bf16(SS.v, vb, accS[ef], 0, 0, 0);
            accP[ef] = __builtin_amdgcn_mfma_f32_16x16x32_bf16(GG.v, vb, accP[ef], 0, 0, 0);
        }
        __builtin_amdgcn_s_setprio(0);

        asm volatile("" ::: "memory");
        __builtin_amdgcn_s_barrier();
        cur ^= 1;
    }

    // ---- within-wave row sums ----
    ssel += __shfl_xor(ssel, 16); ssel += __shfl_xor(ssel, 32);
    spgl += __shfl_xor(spgl, 16); spgl += __shfl_xor(spgl, 32);

    // ---- cross-sg combine via LDS scratch (stride 35 floats) ----
    float* red = (float*)smemB;
    int rbase = (qg * 64 + lid) * 35;
    if (sg == 1) {
        #pragma unroll
        for (int f = 0; f < 4; ++f) {
            *(f32x4*)&red[rbase + f * 4] = accS[f];
            *(f32x4*)&red[rbase + 16 + f * 4] = accP[f];
        }
        red[rbase + 32] = ssel;
        red[rbase + 33] = spgl;
    }
    __syncthreads();
    if (sg == 0) {
        #pragma unroll
        for (int f = 0; f < 4; ++f) {
            f32x4 aS = *(f32x4*)&red[rbase + f * 4];
            f32x4 aP = *(f32x4*)&red[rbase + 16 + f * 4];
            #pragma unroll
            for (int r = 0; r < 4; ++r) {
                accS[f][r] += aS[r];
                accP[f][r] += aP[r];
            }
        }
        ssel += red[rbase + 32];
        spgl += red[rbase + 33];

        float cs = 0.9f / ssel;
        float cp = 0.1f / (spgl + 1e-6f);
        float* ob = out + ((size_t)(b * LL + l0 + qg * 16) * CC + (size_t)h * EE);
        #pragma unroll
        for (int r = 0; r < 4; ++r) {
            float csr = __shfl(cs, 4 * g + r);
            float cpr = __shfl(cp, 4 * g + r);
            #pragma unroll
            for (int f = 0; f < 4; ++f) {
                ob[(size_t)(4 * g + r) * CC + 16 * f + m16] =
                    csr * accS[f][r] + cpr * accP[f][r];
            }
        }
    }
#undef KOFF
#undef VOFF
#undef POFF
#undef STAGE
}

extern "C" void kernel_launch(void* const* d_in, const int* in_sizes, int n_in,
                              void* d_out, int out_size, void* d_ws, size_t ws_size,
                              hipStream_t stream) {
    const float* q = (const float*)d_in[0];
    const float* k = (const float*)d_in[1];
    const float* v = (const float*)d_in[2];
    // d_in[3] = sigma (unused by the reference)
    const float* hurst = (const float*)d_in[4];
    const float* tau = (const float*)d_in[5];
    float* out = (float*)d_out;

    float* ws = (float*)d_ws;
    float* gi     = ws;                            // 1024 (unused)
    float* psi    = gi + LL;                       // 32768
    float* taut   = psi + (size_t)BB * HH * LL;    // 32768
    float* costh  = taut + (size_t)BB * HH * LL;   // 4096 (unused)
    float* sinth  = costh + (size_t)BB * LL;       // 4096 (unused)
    float* part_s = sinth + (size_t)BB * LL;       // 16384
    float* part_c = part_s + (size_t)BB * LL * 4;  // 16384
    float* pcs    = part_c + (size_t)BB * LL * 4;  // 131072
    unsigned short* Qp = (unsigned short*)(pcs + (size_t)BB * HH * LL * 4);
    unsigned short* Kp = Qp + (size_t)BB * HH * LL * 64;   // 2M ushorts each
    unsigned short* Vp = Kp + (size_t)BB * HH * LL * 64;

    // Overlay (consumed by k_hilb BEFORE k_prep writes Qp/Kp/Vp):
    unsigned short* Agh = Qp;
    unsigned short* Agl = Qp + (size_t)1048576;
    unsigned short* Xh  = Kp;
    unsigned short* Xl  = Vp;

    k_pre<<<544, 1024, 0, stream>>>(hurst, tau, q, psi, taut, Agh, Agl, Xh, Xl);
    k_hilb<<<256, 256, 0, stream>>>(q, Agh, Agl, Xh, Xl, part_s, part_c);
    k_prep<<<BB * HH * 16, 256, 0, stream>>>(q, k, v, psi, taut, part_s, part_c,
                                             Qp, Kp, Vp, pcs);
    k_attn<<<BB * HH * (LL / 64), 512, 0, stream>>>(Qp, Kp, Vp, pcs, out);
}

// Round 15
// 80.315 us; speedup vs baseline: 1.0358x; 1.0358x over previous
//
#include <hip/hip_runtime.h>
#include <hip/hip_bf16.h>
#include <math.h>

#define LL 1024
#define BB 4
#define HH 8
#define EE 64
#define CC (HH*EE)  // 512

typedef __attribute__((ext_vector_type(4))) float f32x4;
typedef __attribute__((ext_vector_type(8))) short bf16x8;
typedef __attribute__((ext_vector_type(4))) short bf16x4;

__device__ __forceinline__ unsigned short f2bf(float x) {
    unsigned u = __float_as_uint(x);
    u += 0x7FFFu + ((u >> 16) & 1u);   // round-to-nearest-even
    return (unsigned short)(u >> 16);
}

// global_load_lds 16B: per-lane global src, wave-uniform LDS dest (+lane*16 by HW)
__device__ __forceinline__ void dma16(const void* g, void* l) {
    typedef const __attribute__((address_space(1))) unsigned int* gup;
    typedef __attribute__((address_space(3))) unsigned int* lup;
    gup gp = (gup)(unsigned long long)g;
    lup lp = (lup)(unsigned int)(unsigned long long)l;
    __builtin_amdgcn_global_load_lds(gp, lp, 16, 0, 0);
}

// ---------------- kernel 1 (mega-prep): scan | prepA | prepX | QKV repack ----
// bid<32: psi cumsum + taut.  [32,288): circulant bf16 A tiles.
// [288,544): scrambled-q bf16 X (into d_out).  [544,672): Q/K/V repack (4 tiles/blk).
__global__ __launch_bounds__(1024) void k_pre1(const float* __restrict__ hurst,
                                               const float* __restrict__ tau,
                                               const float* __restrict__ q,
                                               const float* __restrict__ kk,
                                               const float* __restrict__ vv,
                                               float* __restrict__ psi,
                                               float* __restrict__ taut,
                                               unsigned short* __restrict__ Agh,
                                               unsigned short* __restrict__ Agl,
                                               unsigned short* __restrict__ Xh,
                                               unsigned short* __restrict__ Xl,
                                               unsigned short* __restrict__ Qp,
                                               unsigned short* __restrict__ Kp,
                                               unsigned short* __restrict__ Vp) {
    __shared__ __align__(16) char smem[32768];
    int bid = blockIdx.x;
    int t = threadIdx.x;

    if (bid < 32) {
        // ---- scan ----
        float* sh = (float*)smem;
        int bh = bid;
        int b = bh >> 3, h = bh & 7;
        int l = t;
        float hu = hurst[((size_t)b * LL + l) * HH + h];
        float ht = 1.f / (1.f + expf(-hu)) * 0.99f + 0.01f;
        sh[l] = expf(2.0f * ht);
        __syncthreads();
        for (int off = 1; off < LL; off <<= 1) {
            float tmp = (l >= off) ? sh[l - off] : 0.f;
            __syncthreads();
            sh[l] += tmp;
            __syncthreads();
        }
        psi[((size_t)b * HH + h) * LL + l] = sh[l];
        float tv = tau[((size_t)b * LL + l) * HH + h];
        taut[((size_t)b * HH + h) * LL + l] = 1.f / (1.f + expf(-tv)) * 0.9f + 0.1f;
    } else if (bid < 288) {
        // ---- prepA: gi inline, A-frag tiles ----
        float* sh = (float*)smem;
        {
            int d = t;
            float vvv = 0.f;
            if (d & 1) {
                float a = 3.14159265358979323846f * (float)d / (float)LL;
                vvv = (2.0f / (float)LL) * (cosf(a) / sinf(a));
            }
            sh[d] = vvv;
        }
        __syncthreads();
        int bb = bid - 32;               // im*16 + kt
        int im = bb >> 4, kt = bb & 15;
        if (t < 512) {
            int row = t >> 3, gr = t & 7;
            int i = im * 64 + row;
            bf16x8 hv, lv;
            #pragma unroll
            for (int j = 0; j < 8; ++j) {
                int kl = gr * 8 + j;
                float gg = sh[(i - kt * 64 - kl) & 1023];
                unsigned short hh = f2bf(gg);
                hv[j] = (short)hh;
                lv[j] = (short)f2bf(gg - __uint_as_float(((unsigned)hh) << 16));
            }
            size_t base = (size_t)bb * 4096;
            int pos = gr ^ (row & 7);
            *(bf16x8*)&Agh[base + row * 64 + pos * 8] = hv;
            *(bf16x8*)&Agl[base + row * 64 + pos * 8] = lv;
        }
    } else if (bid < 544) {
        // ---- prepX (writes into d_out region) ----
        int bb = bid - 288;              // kt*16 + np
        int kt = bb >> 4, np = bb & 15;
        int bq = np >> 2;
        const float* qb = q + (size_t)bq * LL * CC;
        size_t base = (size_t)bb * 8192;
        int gid = t;
        int nl = gid & 15, nb = (gid >> 4) & 7, kg = gid >> 7;
        int e_n = np * 128 + nb * 16 + nl;
        int cy = (e_n >> 6) & 7;
        int e = e_n & 63;
        bf16x8 hv, lv;
        #pragma unroll
        for (int j = 0; j < 8; ++j) {
            int k2 = kt * 64 + kg * 8 + j;
            int l = ((k2 & 127) << 3) | cy;
            int h2 = k2 >> 7;
            float val = qb[l * 512 + h2 * 64 + e];
            unsigned short hh = f2bf(val);
            hv[j] = (short)hh;
            lv[j] = (short)f2bf(val - __uint_as_float(((unsigned)hh) << 16));
        }
        *(bf16x8*)&Xh[base + (size_t)gid * 8] = hv;
        *(bf16x8*)&Xl[base + (size_t)gid * 8] = lv;
    } else {
        // ---- QKV repack: 4 logical k_prep tiles per block ----
        int bb = bid - 544;              // 0..127
        int sub = t >> 8, tt = t & 255;
        int blk = bb * 4 + sub;          // 0..511
        int tile = blk & 15;
        int bh = blk >> 4;
        int h = bh & 7, b = bh >> 3;
        int l0 = tile * 64;
        unsigned short* vt = (unsigned short*)smem + sub * 4096;

        const float* qg = q + ((size_t)(b * LL + l0) * CC + (size_t)h * EE);
        const float* kg = kk + ((size_t)(b * LL + l0) * CC + (size_t)h * EE);
        const float* vg = vv + ((size_t)(b * LL + l0) * CC + (size_t)h * EE);
        unsigned short* Qo = Qp + ((size_t)bh * LL + l0) * 64;
        unsigned short* Ko = Kp + ((size_t)bh * LL + l0) * 64;
        unsigned short* Vo = Vp + ((size_t)bh * 16 + tile) * 4096;

        const float QS = 0.18033688011112042f;  // 0.125 * log2(e)

        #pragma unroll
        for (int it = 0; it < 2; ++it) {
            int x = it * 256 + tt;
            int row = x >> 3, gr = x & 7;
            int pos = (gr ^ (row & 7)) * 8;
            const float* src = qg + (size_t)row * CC + gr * 8;
            float4 a4 = *(const float4*)src;
            float4 b4 = *(const float4*)(src + 4);
            bf16x8 o;
            o[0] = (short)f2bf(QS * a4.x); o[1] = (short)f2bf(QS * a4.y);
            o[2] = (short)f2bf(QS * a4.z); o[3] = (short)f2bf(QS * a4.w);
            o[4] = (short)f2bf(QS * b4.x); o[5] = (short)f2bf(QS * b4.y);
            o[6] = (short)f2bf(QS * b4.z); o[7] = (short)f2bf(QS * b4.w);
            *(bf16x8*)&Qo[row * 64 + pos] = o;
            src = kg + (size_t)row * CC + gr * 8;
            a4 = *(const float4*)src;
            b4 = *(const float4*)(src + 4);
            o[0] = (short)f2bf(a4.x); o[1] = (short)f2bf(a4.y);
            o[2] = (short)f2bf(a4.z); o[3] = (short)f2bf(a4.w);
            o[4] = (short)f2bf(b4.x); o[5] = (short)f2bf(b4.y);
            o[6] = (short)f2bf(b4.z); o[7] = (short)f2bf(b4.w);
            *(bf16x8*)&Ko[row * 64 + pos] = o;
        }

        #pragma unroll
        for (int it = 0; it < 4; ++it) {
            int x = it * 256 + tt;
            int s = x >> 4, i = x & 15;
            float4 a4 = *(const float4*)(vg + (size_t)s * CC + i * 4);
            int c = s >> 5, g4 = (s >> 2) & 3;
            int jj = ((s >> 4) & 1) * 4 + (s & 3);
            float vals[4] = {a4.x, a4.y, a4.z, a4.w};
            #pragma unroll
            for (int j2 = 0; j2 < 4; ++j2) {
                int e = i * 4 + j2;
                int ef = e >> 4, m16 = e & 15;
                vt[((((ef * 2 + c) * 4 + g4) * 16 + m16) * 8) + jj] = f2bf(vals[j2]);
            }
        }
        __syncthreads();
        #pragma unroll
        for (int it = 0; it < 2; ++it) {
            int x = it * 256 + tt;
            *(bf16x8*)&Vo[x * 8] = *(bf16x8*)&vt[x * 8];
        }
    }
}

// ---------------- kernel 2: MFMA Hilbert conv — counted-vmcnt loop ----------
__global__ __launch_bounds__(256) void k_hilb(const float* __restrict__ q,
                                              const unsigned short* __restrict__ Agh,
                                              const unsigned short* __restrict__ Agl,
                                              const unsigned short* __restrict__ Xh,
                                              const unsigned short* __restrict__ Xl,
                                              float* __restrict__ part_s,
                                              float* __restrict__ part_c) {
    __shared__ __align__(16) char smemB[98304];

    int t = threadIdx.x, lid = t & 63, wv = t >> 6;
    int m16 = lid & 15, g = lid >> 4;
    int wi = wv >> 1, wn = wv & 1;

    int bid = blockIdx.x;
    int xcd = bid & 7, o = bid >> 3;
    int im = ((xcd >> 2) << 3) + (o & 7);
    int np = ((xcd & 3) << 2) + (o >> 3);
    int i0 = im * 64, n0 = np * 128;
    int bq = np >> 2, quad = np & 3;
    const float* qb = q + (size_t)bq * LL * CC;

    const char* Ah_g = (const char*)Agh + (size_t)im * 16 * 8192;
    const char* Al_g = (const char*)Agl + (size_t)im * 16 * 8192;
    const char* Xh_g = (const char*)Xh;
    const char* Xl_g = (const char*)Xl;

#define AHOFF(bf) ((bf) * 49152)
#define ALOFF(bf) ((bf) * 49152 + 8192)
#define XHOFF(bf) ((bf) * 49152 + 16384)
#define XLOFF(bf) ((bf) * 49152 + 32768)
#define STAGE(bf, kt)                                                          \
    {                                                                          \
        size_t xb = ((size_t)(kt) * 16 + np) * 16384;                          \
        _Pragma("unroll")                                                      \
        for (int c = 0; c < 2; ++c) {                                          \
            int ch = wv + 4 * c;                                               \
            dma16(Ah_g + (kt) * 8192 + ch * 1024 + lid * 16,                   \
                  smemB + AHOFF(bf) + ch * 1024);                              \
            dma16(Al_g + (kt) * 8192 + ch * 1024 + lid * 16,                   \
                  smemB + ALOFF(bf) + ch * 1024);                              \
        }                                                                      \
        _Pragma("unroll")                                                      \
        for (int c = 0; c < 4; ++c) {                                          \
            int ch = wv + 4 * c;                                               \
            dma16(Xh_g + xb + ch * 1024 + lid * 16,                            \
                  smemB + XHOFF(bf) + ch * 1024);                              \
            dma16(Xl_g + xb + ch * 1024 + lid * 16,                            \
                  smemB + XLOFF(bf) + ch * 1024);                              \
        }                                                                      \
    }

    STAGE(0, 0);
    __syncthreads();   // prologue: full drain of buf0

    f32x4 acc[2][4];
    #pragma unroll
    for (int mf = 0; mf < 2; ++mf)
        #pragma unroll
        for (int nf = 0; nf < 4; ++nf) acc[mf][nf] = (f32x4){0.f, 0.f, 0.f, 0.f};

    int cur = 0;
    for (int kt = 0; kt < 16; ++kt) {
        if (kt < 15) {
            STAGE(cur ^ 1, kt + 1);
            asm volatile("s_waitcnt vmcnt(12)" ::: "memory");
        } else {
            asm volatile("s_waitcnt vmcnt(0)" ::: "memory");
        }
        __builtin_amdgcn_sched_barrier(0);
        __builtin_amdgcn_s_barrier();
        asm volatile("" ::: "memory");

        const unsigned short* AhL = (const unsigned short*)(smemB + AHOFF(cur));
        const unsigned short* AlL = (const unsigned short*)(smemB + ALOFF(cur));
        const unsigned short* XhL = (const unsigned short*)(smemB + XHOFF(cur));
        const unsigned short* XlL = (const unsigned short*)(smemB + XLOFF(cur));

        __builtin_amdgcn_s_setprio(1);
        #pragma unroll
        for (int s = 0; s < 2; ++s) {
            bf16x8 Ahf[2], Alf[2];
            #pragma unroll
            for (int mf = 0; mf < 2; ++mf) {
                int row = wi * 32 + 16 * mf + m16;
                int pos = (s * 4 + g) ^ (m16 & 7);
                Ahf[mf] = *(bf16x8*)&AhL[row * 64 + pos * 8];
                Alf[mf] = *(bf16x8*)&AlL[row * 64 + pos * 8];
            }
            #pragma unroll
            for (int nf = 0; nf < 4; ++nf) {
                int nb = wn * 4 + nf;
                int goff = (((s * 4 + g) * 8 + nb) * 16 + m16) * 8;
                bf16x8 Bh = *(bf16x8*)&XhL[goff];
                bf16x8 Bl = *(bf16x8*)&XlL[goff];
                #pragma unroll
                for (int mf = 0; mf < 2; ++mf) {
                    acc[mf][nf] = __builtin_amdgcn_mfma_f32_16x16x32_bf16(Ahf[mf], Bh, acc[mf][nf], 0, 0, 0);
                    acc[mf][nf] = __builtin_amdgcn_mfma_f32_16x16x32_bf16(Ahf[mf], Bl, acc[mf][nf], 0, 0, 0);
                    acc[mf][nf] = __builtin_amdgcn_mfma_f32_16x16x32_bf16(Alf[mf], Bh, acc[mf][nf], 0, 0, 0);
                }
            }
        }
        __builtin_amdgcn_s_setprio(0);

        asm volatile("" ::: "memory");
        __builtin_amdgcn_s_barrier();
        cur ^= 1;
    }

    // ---- epilogue: theta partials ----
    float svacc[2][4], cvacc[2][4];
    #pragma unroll
    for (int mf = 0; mf < 2; ++mf)
        #pragma unroll
        for (int r = 0; r < 4; ++r) { svacc[mf][r] = 0.f; cvacc[mf][r] = 0.f; }

    #pragma unroll
    for (int mf = 0; mf < 2; ++mf) {
        #pragma unroll
        for (int nf = 0; nf < 4; ++nf) {
            #pragma unroll
            for (int r = 0; r < 4; ++r) {
                float iv = acc[mf][nf][r];
                int ig = i0 + wi * 32 + 16 * mf + 4 * g + r;
                int ng = n0 + wn * 64 + 16 * nf + m16;
                int cc2 = ng & 511;
                int cy = cc2 >> 6, e = cc2 & 63;
                int l = ((ig & 127) << 3) | cy;
                int h2 = ig >> 7;
                float re = qb[l * 512 + h2 * 64 + e];
                float rr = sqrtf(re * re + iv * iv);
                float sv, cv;
                if (rr > 0.f) { sv = iv / rr; cv = re / rr; }
                else { sv = 0.f; cv = 1.f; }
                svacc[mf][r] += sv;
                cvacc[mf][r] += cv;
            }
        }
    }
    __syncthreads();   // smemB reuse
    float* psv = (float*)smemB;
    float* pcv = (float*)(smemB + 512);
    #pragma unroll
    for (int mf = 0; mf < 2; ++mf) {
        #pragma unroll
        for (int r = 0; r < 4; ++r) {
            float s = svacc[mf][r], c = cvacc[mf][r];
            s += __shfl_xor(s, 1); s += __shfl_xor(s, 2);
            s += __shfl_xor(s, 4); s += __shfl_xor(s, 8);
            c += __shfl_xor(c, 1); c += __shfl_xor(c, 2);
            c += __shfl_xor(c, 4); c += __shfl_xor(c, 8);
            if (m16 == 0) {
                psv[wv * 32 + 16 * mf + 4 * g + r] = s;
                pcv[wv * 32 + 16 * mf + 4 * g + r] = c;
            }
        }
    }
    __syncthreads();
    if (t < 64) {
        int wg = (t >> 5) * 2;
        float s = psv[wg * 32 + (t & 31)] + psv[(wg + 1) * 32 + (t & 31)];
        float c = pcv[wg * 32 + (t & 31)] + pcv[(wg + 1) * 32 + (t & 31)];
        size_t oidx = ((size_t)bq * 1024 + (i0 + t)) * 4 + quad;
        part_s[oidx] = s;
        part_c[oidx] = c;
    }
#undef AHOFF
#undef ALOFF
#undef XHOFF
#undef XLOFF
#undef STAGE
}

// ---------------- kernel 3: pcs finalize (theta + per-row params) ----------
__global__ __launch_bounds__(1024) void k_pcs(const float* __restrict__ psi,
                                              const float* __restrict__ taut,
                                              const float* __restrict__ part_s,
                                              const float* __restrict__ part_c,
                                              float* __restrict__ pcs) {
    int tid = blockIdx.x * 1024 + threadIdx.x;   // 0..32767 = bh*1024 + l
    int bh = tid >> 10, l = tid & 1023;
    int b = bh >> 3;
    float ss = 0.f, cc2 = 0.f;
    size_t pbase = ((size_t)b * 1024 + l) * 4;
    #pragma unroll
    for (int qd = 0; qd < 4; ++qd) {
        ss += part_s[pbase + qd];
        cc2 += part_c[pbase + qd];
    }
    float r2 = ss * ss + cc2 * cc2;
    float cth = 1.f, sth = 0.f;
    if (r2 > 0.f) {
        float rn = rsqrtf(r2);
        cth = cc2 * rn; sth = ss * rn;
    }
    float ta = taut[tid];
    float4 o;
    o.x = psi[tid] * 0.8493218003f;    // sqrt(log2e/2)
    o.y = cth;
    o.z = sth;
    o.w = 0.3606737602f / (ta * ta);   // log2e/(4 tau^2)
    *(float4*)&pcs[(size_t)tid * 4] = o;
}

// ---------------- kernel 4: MFMA flash attn (round-13, validated) ----------
__global__ __launch_bounds__(256, 3) void k_attn(const unsigned short* __restrict__ Qp,
                                                 const unsigned short* __restrict__ Kp,
                                                 const unsigned short* __restrict__ Vp,
                                                 const float* __restrict__ pcs,
                                                 float* __restrict__ out) {
    __shared__ __align__(16) char smemB[43008];

    int t = threadIdx.x;
    int lid = t & 63;
    int wv = t >> 6;
    int m16 = lid & 15;
    int g = lid >> 4;

    int bid = blockIdx.x;
    int blk = (bid & 7) * 64 + (bid >> 3);
    int qt = blk & 15;
    int bh = blk >> 4;
    int h = bh & 7, b = bh >> 3;
    int l0 = qt * 64;

    const char* Qg = (const char*)(Qp + ((size_t)bh * LL + l0) * 64);
    const char* Kg = (const char*)(Kp + (size_t)bh * LL * 64);
    const char* Vg = (const char*)(Vp + (size_t)bh * LL * 64);
    const float* pcsg = pcs + (size_t)bh * LL * 4;

    int qrow = wv * 16 + m16;
    float4 myq = *(const float4*)&pcsg[(size_t)(l0 + qrow) * 4];
    float psiq = myq.x, cq = myq.y, sq = myq.z;
    float wgt = myq.w, nwgt = -myq.w;

#define KOFF(bf) (8192 + (bf) * 8192)
#define VOFF(bf) (24576 + (bf) * 8192)
#define POFF(bf) (40960 + (bf) * 1024)
#define STAGE(bf, tile)                                                        \
    {                                                                          \
        const char* kb8 = Kg + (tile) * 8192;                                  \
        const char* vb8 = Vg + (tile) * 8192;                                  \
        _Pragma("unroll")                                                      \
        for (int c = 0; c < 2; ++c) {                                          \
            int ch = wv + 4 * c;                                               \
            dma16(kb8 + ch * 1024 + lid * 16, smemB + KOFF(bf) + ch * 1024);   \
            dma16(vb8 + ch * 1024 + lid * 16, smemB + VOFF(bf) + ch * 1024);   \
        }                                                                      \
        dma16((const char*)pcsg + (tile) * 1024 + lid * 16, smemB + POFF(bf)); \
    }

    #pragma unroll
    for (int c = 0; c < 2; ++c) {
        int ch = wv + 4 * c;
        dma16(Qg + ch * 1024 + lid * 16, smemB + ch * 1024);
    }
    STAGE(0, 0);
    __syncthreads();   // full drain once (prologue)

    const unsigned short* qlds = (const unsigned short*)smemB;
    bf16x8 qf[2];
    #pragma unroll
    for (int ec = 0; ec < 2; ++ec) {
        int pos = (4 * ec + g) ^ (m16 & 7);
        qf[ec] = *(bf16x8*)&qlds[(wv * 16 + m16) * 64 + pos * 8];
    }

    f32x4 accS[4], accP[4];
    #pragma unroll
    for (int f = 0; f < 4; ++f) {
        accS[f] = (f32x4){0.f, 0.f, 0.f, 0.f};
        accP[f] = (f32x4){0.f, 0.f, 0.f, 0.f};
    }
    float ssel = 0.f, spgl = 0.f;
    int cur = 0;

    for (int tile = 0; tile < 16; ++tile) {
        if (tile < 15) {
            STAGE(cur ^ 1, tile + 1);
            asm volatile("s_waitcnt vmcnt(5)" ::: "memory");
        } else {
            asm volatile("s_waitcnt vmcnt(0)" ::: "memory");
        }
        __builtin_amdgcn_sched_barrier(0);
        __builtin_amdgcn_s_barrier();
        asm volatile("" ::: "memory");

        const unsigned short* kbuf = (const unsigned short*)(smemB + KOFF(cur));
        const unsigned short* vbuf = (const unsigned short*)(smemB + VOFF(cur));
        const float* pcb = (const float*)(smemB + POFF(cur));

        f32x4 st[4];
        #pragma unroll
        for (int f = 0; f < 4; ++f) st[f] = (f32x4){0.f, 0.f, 0.f, 0.f};
        __builtin_amdgcn_s_setprio(1);
        #pragma unroll
        for (int ec = 0; ec < 2; ++ec) {
            int pos = (4 * ec + g) ^ (m16 & 7);
            #pragma unroll
            for (int f = 0; f < 4; ++f) {
                bf16x8 ka = *(bf16x8*)&kbuf[(16 * f + m16) * 64 + pos * 8];
                st[f] = __builtin_amdgcn_mfma_f32_16x16x32_bf16(ka, qf[ec], st[f], 0, 0, 0);
            }
        }
        __builtin_amdgcn_s_setprio(0);

        float psum = 0.f;
        float ps_[16], pg_[16];
        #pragma unroll
        for (int f = 0; f < 4; ++f) {
            #pragma unroll
            for (int r = 0; r < 4; ++r) {
                float4 pc4 = *(const float4*)&pcb[(16 * f + 4 * g + r) * 4];
                float p = exp2f(st[f][r]);
                psum += p;
                float d = psiq - pc4.x;
                float cd = fmaf(cq, pc4.y, sq * pc4.z);
                float arg = fmaf(-d, d, fmaf(wgt, cd, nwgt));  // w*cd - w - d^2
                float pgv = exp2f(arg);
                spgl += pgv;
                ps_[f * 4 + r] = p;
                pg_[f * 4 + r] = pgv;
            }
        }
        ssel += psum;

        union PK8 { unsigned w[8]; bf16x8 v[2]; } SS, GG;
        #pragma unroll
        for (int i2 = 0; i2 < 8; ++i2) {
            __hip_bfloat162 hs = __float22bfloat162_rn(
                make_float2(ps_[2 * i2], ps_[2 * i2 + 1]));
            __hip_bfloat162 hg = __float22bfloat162_rn(
                make_float2(pg_[2 * i2], pg_[2 * i2 + 1]));
            unsigned ws2, wg2;
            __builtin_memcpy(&ws2, &hs, 4);
            __builtin_memcpy(&wg2, &hg, 4);
            SS.w[i2] = ws2;
            GG.w[i2] = wg2;
        }

        __builtin_amdgcn_s_setprio(1);
        #pragma unroll
        for (int c = 0; c < 2; ++c) {
            #pragma unroll
            for (int ef = 0; ef < 4; ++ef) {
                bf16x8 vb = *(bf16x8*)&vbuf[(((ef * 2 + c) * 4 + g) * 16 + m16) * 8];
                accS[ef] = __builtin_amdgcn_mfma_f32_16x16x32_bf16(SS.v[c], vb, accS[ef], 0, 0, 0);
                accP[ef] = __builtin_amdgcn_mfma_f32_16x16x32_bf16(GG.v[c], vb, accP[ef], 0, 0, 0);
            }
        }
        __builtin_amdgcn_s_setprio(0);

        asm volatile("" ::: "memory");
        __builtin_amdgcn_s_barrier();
        cur ^= 1;
    }

    ssel += __shfl_xor(ssel, 16); ssel += __shfl_xor(ssel, 32);
    spgl += __shfl_xor(spgl, 16); spgl += __shfl_xor(spgl, 32);
    float cs = 0.9f / ssel;
    float cp = 0.1f / (spgl + 1e-6f);
    float* ob = out + ((size_t)(b * LL + l0 + wv * 16) * CC + (size_t)h * EE);
    #pragma unroll
    for (int r = 0; r < 4; ++r) {
        float csr = __shfl(cs, 4 * g + r);
        float cpr = __shfl(cp, 4 * g + r);
        #pragma unroll
        for (int f = 0; f < 4; ++f) {
            ob[(size_t)(4 * g + r) * CC + 16 * f + m16] =
                csr * accS[f][r] + cpr * accP[f][r];
        }
    }
#undef KOFF
#undef VOFF
#undef POFF
#undef STAGE
}

extern "C" void kernel_launch(void* const* d_in, const int* in_sizes, int n_in,
                              void* d_out, int out_size, void* d_ws, size_t ws_size,
                              hipStream_t stream) {
    const float* q = (const float*)d_in[0];
    const float* k = (const float*)d_in[1];
    const float* v = (const float*)d_in[2];
    // d_in[3] = sigma (unused by the reference)
    const float* hurst = (const float*)d_in[4];
    const float* tau = (const float*)d_in[5];
    float* out = (float*)d_out;

    float* ws = (float*)d_ws;
    float* gi     = ws;                            // 1024 (unused slot)
    float* psi    = gi + LL;                       // 32768
    float* taut   = psi + (size_t)BB * HH * LL;    // 32768
    float* costh  = taut + (size_t)BB * HH * LL;   // 4096 (unused slot)
    float* sinth  = costh + (size_t)BB * LL;       // 4096 (unused slot)
    float* part_s = sinth + (size_t)BB * LL;       // 16384
    float* part_c = part_s + (size_t)BB * LL * 4;  // 16384
    float* pcs    = part_c + (size_t)BB * LL * 4;  // 131072
    unsigned short* Qp = (unsigned short*)(pcs + (size_t)BB * HH * LL * 4);
    unsigned short* Kp = Qp + (size_t)BB * HH * LL * 64;   // 2M ushorts each
    unsigned short* Vp = Kp + (size_t)BB * HH * LL * 64;
    // A tiles get fresh ws space (no overlay); X lives in d_out (exact 8MB fit,
    // fully overwritten by k_attn afterwards).
    unsigned short* Agh = Vp + (size_t)BB * HH * LL * 64;  // 1M ushorts
    unsigned short* Agl = Agh + (size_t)1048576;           // 1M ushorts
    unsigned short* Xh  = (unsigned short*)d_out;          // 2M ushorts
    unsigned short* Xl  = Xh + (size_t)2097152;            // 2M ushorts

    k_pre1<<<672, 1024, 0, stream>>>(hurst, tau, q, k, v, psi, taut,
                                     Agh, Agl, Xh, Xl, Qp, Kp, Vp);
    k_hilb<<<256, 256, 0, stream>>>(q, Agh, Agl, Xh, Xl, part_s, part_c);
    k_pcs<<<32, 1024, 0, stream>>>(psi, taut, part_s, part_c, pcs);
    k_attn<<<BB * HH * (LL / 64), 256, 0, stream>>>(Qp, Kp, Vp, pcs, out);
}

// Round 16
// 74.935 us; speedup vs baseline: 1.1101x; 1.0718x over previous
//
#include <hip/hip_runtime.h>
#include <hip/hip_bf16.h>
#include <math.h>

#define LL 1024
#define BB 4
#define HH 8
#define EE 64
#define CC (HH*EE)  // 512

typedef __attribute__((ext_vector_type(4))) float f32x4;
typedef __attribute__((ext_vector_type(8))) short bf16x8;
typedef __attribute__((ext_vector_type(4))) short bf16x4;

__device__ __forceinline__ unsigned short f2bf(float x) {
    unsigned u = __float_as_uint(x);
    u += 0x7FFFu + ((u >> 16) & 1u);   // round-to-nearest-even
    return (unsigned short)(u >> 16);
}

// global_load_lds 16B: per-lane global src, wave-uniform LDS dest (+lane*16 by HW)
__device__ __forceinline__ void dma16(const void* g, void* l) {
    typedef const __attribute__((address_space(1))) unsigned int* gup;
    typedef __attribute__((address_space(3))) unsigned int* lup;
    gup gp = (gup)(unsigned long long)g;
    lup lp = (lup)(unsigned int)(unsigned long long)l;
    __builtin_amdgcn_global_load_lds(gp, lp, 16, 0, 0);
}

// ---------------- kernel 1 (mega-prep): scan | prepA | prepX | QKV repack ----
__global__ __launch_bounds__(1024) void k_pre1(const float* __restrict__ hurst,
                                               const float* __restrict__ tau,
                                               const float* __restrict__ q,
                                               const float* __restrict__ kk,
                                               const float* __restrict__ vv,
                                               float* __restrict__ psi,
                                               float* __restrict__ taut,
                                               unsigned short* __restrict__ Agh,
                                               unsigned short* __restrict__ Agl,
                                               unsigned short* __restrict__ Xh,
                                               unsigned short* __restrict__ Xl,
                                               unsigned short* __restrict__ Qp,
                                               unsigned short* __restrict__ Kp,
                                               unsigned short* __restrict__ Vp) {
    __shared__ __align__(16) char smem[32768];
    int bid = blockIdx.x;
    int t = threadIdx.x;

    if (bid < 32) {
        // ---- scan ----
        float* sh = (float*)smem;
        int bh = bid;
        int b = bh >> 3, h = bh & 7;
        int l = t;
        float hu = hurst[((size_t)b * LL + l) * HH + h];
        float ht = 1.f / (1.f + expf(-hu)) * 0.99f + 0.01f;
        sh[l] = expf(2.0f * ht);
        __syncthreads();
        for (int off = 1; off < LL; off <<= 1) {
            float tmp = (l >= off) ? sh[l - off] : 0.f;
            __syncthreads();
            sh[l] += tmp;
            __syncthreads();
        }
        psi[((size_t)b * HH + h) * LL + l] = sh[l];
        float tv = tau[((size_t)b * LL + l) * HH + h];
        taut[((size_t)b * HH + h) * LL + l] = 1.f / (1.f + expf(-tv)) * 0.9f + 0.1f;
    } else if (bid < 288) {
        // ---- prepA: gi inline, A-frag tiles ----
        float* sh = (float*)smem;
        {
            int d = t;
            float vvv = 0.f;
            if (d & 1) {
                float a = 3.14159265358979323846f * (float)d / (float)LL;
                vvv = (2.0f / (float)LL) * (cosf(a) / sinf(a));
            }
            sh[d] = vvv;
        }
        __syncthreads();
        int bb = bid - 32;               // im*16 + kt
        int im = bb >> 4, kt = bb & 15;
        if (t < 512) {
            int row = t >> 3, gr = t & 7;
            int i = im * 64 + row;
            bf16x8 hv, lv;
            #pragma unroll
            for (int j = 0; j < 8; ++j) {
                int kl = gr * 8 + j;
                float gg = sh[(i - kt * 64 - kl) & 1023];
                unsigned short hh = f2bf(gg);
                hv[j] = (short)hh;
                lv[j] = (short)f2bf(gg - __uint_as_float(((unsigned)hh) << 16));
            }
            size_t base = (size_t)bb * 4096;
            int pos = gr ^ (row & 7);
            *(bf16x8*)&Agh[base + row * 64 + pos * 8] = hv;
            *(bf16x8*)&Agl[base + row * 64 + pos * 8] = lv;
        }
    } else if (bid < 544) {
        // ---- prepX (into d_out region) ----
        int bb = bid - 288;              // kt*16 + np
        int kt = bb >> 4, np = bb & 15;
        int bq = np >> 2;
        const float* qb = q + (size_t)bq * LL * CC;
        size_t base = (size_t)bb * 8192;
        int gid = t;
        int nl = gid & 15, nb = (gid >> 4) & 7, kg = gid >> 7;
        int e_n = np * 128 + nb * 16 + nl;
        int cy = (e_n >> 6) & 7;
        int e = e_n & 63;
        bf16x8 hv, lv;
        #pragma unroll
        for (int j = 0; j < 8; ++j) {
            int k2 = kt * 64 + kg * 8 + j;
            int l = ((k2 & 127) << 3) | cy;
            int h2 = k2 >> 7;
            float val = qb[l * 512 + h2 * 64 + e];
            unsigned short hh = f2bf(val);
            hv[j] = (short)hh;
            lv[j] = (short)f2bf(val - __uint_as_float(((unsigned)hh) << 16));
        }
        *(bf16x8*)&Xh[base + (size_t)gid * 8] = hv;
        *(bf16x8*)&Xl[base + (size_t)gid * 8] = lv;
    } else {
        // ---- QKV repack: 4 logical prep tiles per block ----
        int bb = bid - 544;              // 0..127
        int sub = t >> 8, tt = t & 255;
        int blk = bb * 4 + sub;          // 0..511
        int tile = blk & 15;
        int bh = blk >> 4;
        int h = bh & 7, b = bh >> 3;
        int l0 = tile * 64;
        unsigned short* vt = (unsigned short*)smem + sub * 4096;

        const float* qg = q + ((size_t)(b * LL + l0) * CC + (size_t)h * EE);
        const float* kg = kk + ((size_t)(b * LL + l0) * CC + (size_t)h * EE);
        const float* vg = vv + ((size_t)(b * LL + l0) * CC + (size_t)h * EE);
        unsigned short* Qo = Qp + ((size_t)bh * LL + l0) * 64;
        unsigned short* Ko = Kp + ((size_t)bh * LL + l0) * 64;
        unsigned short* Vo = Vp + ((size_t)bh * 16 + tile) * 4096;

        const float QS = 0.18033688011112042f;  // 0.125 * log2(e)

        #pragma unroll
        for (int it = 0; it < 2; ++it) {
            int x = it * 256 + tt;
            int row = x >> 3, gr = x & 7;
            int pos = (gr ^ (row & 7)) * 8;
            const float* src = qg + (size_t)row * CC + gr * 8;
            float4 a4 = *(const float4*)src;
            float4 b4 = *(const float4*)(src + 4);
            bf16x8 o;
            o[0] = (short)f2bf(QS * a4.x); o[1] = (short)f2bf(QS * a4.y);
            o[2] = (short)f2bf(QS * a4.z); o[3] = (short)f2bf(QS * a4.w);
            o[4] = (short)f2bf(QS * b4.x); o[5] = (short)f2bf(QS * b4.y);
            o[6] = (short)f2bf(QS * b4.z); o[7] = (short)f2bf(QS * b4.w);
            *(bf16x8*)&Qo[row * 64 + pos] = o;
            src = kg + (size_t)row * CC + gr * 8;
            a4 = *(const float4*)src;
            b4 = *(const float4*)(src + 4);
            o[0] = (short)f2bf(a4.x); o[1] = (short)f2bf(a4.y);
            o[2] = (short)f2bf(a4.z); o[3] = (short)f2bf(a4.w);
            o[4] = (short)f2bf(b4.x); o[5] = (short)f2bf(b4.y);
            o[6] = (short)f2bf(b4.z); o[7] = (short)f2bf(b4.w);
            *(bf16x8*)&Ko[row * 64 + pos] = o;
        }

        #pragma unroll
        for (int it = 0; it < 4; ++it) {
            int x = it * 256 + tt;
            int s = x >> 4, i = x & 15;
            float4 a4 = *(const float4*)(vg + (size_t)s * CC + i * 4);
            int c = s >> 5, g4 = (s >> 2) & 3;
            int jj = ((s >> 4) & 1) * 4 + (s & 3);
            float vals[4] = {a4.x, a4.y, a4.z, a4.w};
            #pragma unroll
            for (int j2 = 0; j2 < 4; ++j2) {
                int e = i * 4 + j2;
                int ef = e >> 4, m16 = e & 15;
                vt[((((ef * 2 + c) * 4 + g4) * 16 + m16) * 8) + jj] = f2bf(vals[j2]);
            }
        }
        __syncthreads();
        #pragma unroll
        for (int it = 0; it < 2; ++it) {
            int x = it * 256 + tt;
            *(bf16x8*)&Vo[x * 8] = *(bf16x8*)&vt[x * 8];
        }
    }
}

// ---------------- kernel 2: MFMA Hilbert conv — 64-n blocks, 2 blk/CU --------
// Block (im, np8): 64 i x 64 n. Grid 512. Per-buf 32KB (A hi/lo 16K + X hi/lo 16K).
__global__ __launch_bounds__(256) void k_hilb(const float* __restrict__ q,
                                              const unsigned short* __restrict__ Agh,
                                              const unsigned short* __restrict__ Agl,
                                              const unsigned short* __restrict__ Xh,
                                              const unsigned short* __restrict__ Xl,
                                              float* __restrict__ part_s,
                                              float* __restrict__ part_c) {
    __shared__ __align__(16) char smemB[65536];

    int t = threadIdx.x, lid = t & 63, wv = t >> 6;
    int m16 = lid & 15, g = lid >> 4;
    int wi = wv >> 1, wn = wv & 1;

    int bid = blockIdx.x;
    int xcd = bid & 7, o = bid >> 3;
    int im  = ((xcd >> 2) << 3) + (o & 7);    // 0..15
    int np8 = ((xcd & 3) << 3) + (o >> 3);    // 0..31
    int i0 = im * 64, n0 = np8 * 64;
    int bq = np8 >> 3, oct = np8 & 7;
    int np = np8 >> 1, nb0 = (np8 & 1) * 4;
    const float* qb = q + (size_t)bq * LL * CC;

    const char* Ah_g = (const char*)Agh + (size_t)im * 16 * 8192;
    const char* Al_g = (const char*)Agl + (size_t)im * 16 * 8192;
    const char* Xh_g = (const char*)Xh;
    const char* Xl_g = (const char*)Xl;

#define AHOFF(bf) ((bf) * 32768)
#define ALOFF(bf) ((bf) * 32768 + 8192)
#define XHOFF(bf) ((bf) * 32768 + 16384)
#define XLOFF(bf) ((bf) * 32768 + 24576)
// per wave: 2 A-hi, 2 A-lo, 2 X-hi, 2 X-lo = 8 dma
#define STAGE(bf, kt)                                                          \
    {                                                                          \
        size_t xb = ((size_t)(kt) * 16 + np) * 16384;                          \
        _Pragma("unroll")                                                      \
        for (int c = 0; c < 2; ++c) {                                          \
            int ch = wv + 4 * c;                                               \
            dma16(Ah_g + (kt) * 8192 + ch * 1024 + lid * 16,                   \
                  smemB + AHOFF(bf) + ch * 1024);                              \
            dma16(Al_g + (kt) * 8192 + ch * 1024 + lid * 16,                   \
                  smemB + ALOFF(bf) + ch * 1024);                              \
            dma16(Xh_g + xb + (ch * 8 + nb0) * 256 + lid * 16,                 \
                  smemB + XHOFF(bf) + ch * 1024);                              \
            dma16(Xl_g + xb + (ch * 8 + nb0) * 256 + lid * 16,                 \
                  smemB + XLOFF(bf) + ch * 1024);                              \
        }                                                                      \
    }

    STAGE(0, 0);
    __syncthreads();   // prologue: full drain

    f32x4 acc[2][2];
    #pragma unroll
    for (int mf = 0; mf < 2; ++mf)
        #pragma unroll
        for (int nf = 0; nf < 2; ++nf) acc[mf][nf] = (f32x4){0.f, 0.f, 0.f, 0.f};

    int cur = 0;
    for (int kt = 0; kt < 16; ++kt) {
        if (kt < 15) {
            STAGE(cur ^ 1, kt + 1);
            asm volatile("s_waitcnt vmcnt(8)" ::: "memory");
        } else {
            asm volatile("s_waitcnt vmcnt(0)" ::: "memory");
        }
        __builtin_amdgcn_sched_barrier(0);
        __builtin_amdgcn_s_barrier();
        asm volatile("" ::: "memory");

        const unsigned short* AhL = (const unsigned short*)(smemB + AHOFF(cur));
        const unsigned short* AlL = (const unsigned short*)(smemB + ALOFF(cur));
        const unsigned short* XhL = (const unsigned short*)(smemB + XHOFF(cur));
        const unsigned short* XlL = (const unsigned short*)(smemB + XLOFF(cur));

        __builtin_amdgcn_s_setprio(1);
        #pragma unroll
        for (int s = 0; s < 2; ++s) {
            bf16x8 Ahf[2], Alf[2];
            #pragma unroll
            for (int mf = 0; mf < 2; ++mf) {
                int row = wi * 32 + 16 * mf + m16;
                int pos = (s * 4 + g) ^ (m16 & 7);
                Ahf[mf] = *(bf16x8*)&AhL[row * 64 + pos * 8];
                Alf[mf] = *(bf16x8*)&AlL[row * 64 + pos * 8];
            }
            #pragma unroll
            for (int nf = 0; nf < 2; ++nf) {
                int nbl = wn * 2 + nf;   // 0..3
                int goff = (((s * 4 + g) * 4 + nbl) * 16 + m16) * 8;
                bf16x8 Bh = *(bf16x8*)&XhL[goff];
                bf16x8 Bl = *(bf16x8*)&XlL[goff];
                #pragma unroll
                for (int mf = 0; mf < 2; ++mf) {
                    acc[mf][nf] = __builtin_amdgcn_mfma_f32_16x16x32_bf16(Ahf[mf], Bh, acc[mf][nf], 0, 0, 0);
                    acc[mf][nf] = __builtin_amdgcn_mfma_f32_16x16x32_bf16(Ahf[mf], Bl, acc[mf][nf], 0, 0, 0);
                    acc[mf][nf] = __builtin_amdgcn_mfma_f32_16x16x32_bf16(Alf[mf], Bh, acc[mf][nf], 0, 0, 0);
                }
            }
        }
        __builtin_amdgcn_s_setprio(0);

        asm volatile("" ::: "memory");
        __builtin_amdgcn_s_barrier();
        cur ^= 1;
    }

    // ---- epilogue: theta partials over the block's 64 channels ----
    float svacc[2][4], cvacc[2][4];
    #pragma unroll
    for (int mf = 0; mf < 2; ++mf)
        #pragma unroll
        for (int r = 0; r < 4; ++r) { svacc[mf][r] = 0.f; cvacc[mf][r] = 0.f; }

    #pragma unroll
    for (int mf = 0; mf < 2; ++mf) {
        #pragma unroll
        for (int nf = 0; nf < 2; ++nf) {
            #pragma unroll
            for (int r = 0; r < 4; ++r) {
                float iv = acc[mf][nf][r];
                int ig = i0 + wi * 32 + 16 * mf + 4 * g + r;
                int ng = n0 + (wn * 2 + nf) * 16 + m16;
                int cc2 = ng & 511;
                int cy = cc2 >> 6, e = cc2 & 63;
                int l = ((ig & 127) << 3) | cy;
                int h2 = ig >> 7;
                float re = qb[l * 512 + h2 * 64 + e];
                float rr = sqrtf(re * re + iv * iv);
                float sv, cv;
                if (rr > 0.f) { sv = iv / rr; cv = re / rr; }
                else { sv = 0.f; cv = 1.f; }
                svacc[mf][r] += sv;
                cvacc[mf][r] += cv;
            }
        }
    }
    __syncthreads();   // smemB reuse
    float* psv = (float*)smemB;
    float* pcv = (float*)(smemB + 512);
    #pragma unroll
    for (int mf = 0; mf < 2; ++mf) {
        #pragma unroll
        for (int r = 0; r < 4; ++r) {
            float s = svacc[mf][r], c = cvacc[mf][r];
            s += __shfl_xor(s, 1); s += __shfl_xor(s, 2);
            s += __shfl_xor(s, 4); s += __shfl_xor(s, 8);
            c += __shfl_xor(c, 1); c += __shfl_xor(c, 2);
            c += __shfl_xor(c, 4); c += __shfl_xor(c, 8);
            if (m16 == 0) {
                psv[wv * 32 + 16 * mf + 4 * g + r] = s;
                pcv[wv * 32 + 16 * mf + 4 * g + r] = c;
            }
        }
    }
    __syncthreads();
    if (t < 64) {
        int wg = (t >> 5) * 2;
        float s = psv[wg * 32 + (t & 31)] + psv[(wg + 1) * 32 + (t & 31)];
        float c = pcv[wg * 32 + (t & 31)] + pcv[(wg + 1) * 32 + (t & 31)];
        size_t oidx = ((size_t)bq * 1024 + (i0 + t)) * 8 + oct;
        part_s[oidx] = s;
        part_c[oidx] = c;
    }
#undef AHOFF
#undef ALOFF
#undef XHOFF
#undef XLOFF
#undef STAGE
}

// ---------------- kernel 3: pcs finalize (theta + per-row params) ----------
__global__ __launch_bounds__(1024) void k_pcs(const float* __restrict__ psi,
                                              const float* __restrict__ taut,
                                              const float* __restrict__ part_s,
                                              const float* __restrict__ part_c,
                                              float* __restrict__ pcs) {
    int tid = blockIdx.x * 1024 + threadIdx.x;   // bh*1024 + l
    int bh = tid >> 10, l = tid & 1023;
    int b = bh >> 3;
    float ss = 0.f, cc2 = 0.f;
    size_t pbase = ((size_t)b * 1024 + l) * 8;
    #pragma unroll
    for (int qd = 0; qd < 8; ++qd) {
        ss += part_s[pbase + qd];
        cc2 += part_c[pbase + qd];
    }
    float r2 = ss * ss + cc2 * cc2;
    float cth = 1.f, sth = 0.f;
    if (r2 > 0.f) {
        float rn = rsqrtf(r2);
        cth = cc2 * rn; sth = ss * rn;
    }
    float ta = taut[tid];
    float4 o;
    o.x = psi[tid] * 0.8493218003f;    // sqrt(log2e/2)
    o.y = cth;
    o.z = sth;
    o.w = 0.3606737602f / (ta * ta);   // log2e/(4 tau^2)
    *(float4*)&pcs[(size_t)tid * 4] = o;
}

// ---------------- kernel 4: MFMA flash attn — ST=128, 8 barrier pairs --------
__global__ __launch_bounds__(256) void k_attn(const unsigned short* __restrict__ Qp,
                                              const unsigned short* __restrict__ Kp,
                                              const unsigned short* __restrict__ Vp,
                                              const float* __restrict__ pcs,
                                              float* __restrict__ out) {
    // k dbuf 0..32767 | v dbuf 32768..65535 | pcs dbuf 65536..69631
    __shared__ __align__(16) char smemB[69632];

    int t = threadIdx.x;
    int lid = t & 63;
    int wv = t >> 6;
    int m16 = lid & 15;
    int g = lid >> 4;

    int bid = blockIdx.x;
    int blk = (bid & 7) * 64 + (bid >> 3);
    int qt = blk & 15;
    int bh = blk >> 4;
    int h = bh & 7, b = bh >> 3;
    int l0 = qt * 64;

    const char* Qg = (const char*)(Qp + ((size_t)bh * LL + l0) * 64);
    const char* Kg = (const char*)(Kp + (size_t)bh * LL * 64);
    const char* Vg = (const char*)(Vp + (size_t)bh * LL * 64);
    const float* pcsg = pcs + (size_t)bh * LL * 4;

    int qrow = wv * 16 + m16;
    float4 myq = *(const float4*)&pcsg[(size_t)(l0 + qrow) * 4];
    float psiq = myq.x, cq = myq.y, sq = myq.z;
    float wgt = myq.w, nwgt = -myq.w;

#define KOFF(bf) ((bf) * 16384)
#define VOFF(bf) (32768 + (bf) * 16384)
#define POFF(bf) (65536 + (bf) * 2048)
// per wave: 4 K chunks + 4 V chunks + 1 pcs = 9 dma
#define STAGE(bf, it)                                                          \
    {                                                                          \
        const char* kb8 = Kg + (it) * 16384;                                   \
        const char* vb8 = Vg + (it) * 16384;                                   \
        _Pragma("unroll")                                                      \
        for (int c = 0; c < 4; ++c) {                                          \
            int ch = wv + 4 * c;                                               \
            dma16(kb8 + ch * 1024 + lid * 16, smemB + KOFF(bf) + ch * 1024);   \
            dma16(vb8 + ch * 1024 + lid * 16, smemB + VOFF(bf) + ch * 1024);   \
        }                                                                      \
        dma16((const char*)pcsg + (it) * 2048 + (wv & 1) * 1024 + lid * 16,    \
              smemB + POFF(bf) + (wv & 1) * 1024);                             \
    }

    // Q B-frags straight from global (Qp layout == frag layout; r14-validated)
    bf16x8 qf[2];
    #pragma unroll
    for (int ec = 0; ec < 2; ++ec) {
        int pos = (4 * ec + g) ^ (m16 & 7);
        qf[ec] = *(const bf16x8*)(Qg + ((wv * 16 + m16) * 64 + pos * 8) * 2);
    }
    STAGE(0, 0);
    __syncthreads();   // prologue: full drain

    f32x4 accS[4], accP[4];
    #pragma unroll
    for (int f = 0; f < 4; ++f) {
        accS[f] = (f32x4){0.f, 0.f, 0.f, 0.f};
        accP[f] = (f32x4){0.f, 0.f, 0.f, 0.f};
    }
    float ssel = 0.f, spgl = 0.f;
    int cur = 0;

    for (int it = 0; it < 8; ++it) {
        if (it < 7) {
            STAGE(cur ^ 1, it + 1);
            asm volatile("s_waitcnt vmcnt(9)" ::: "memory");
        } else {
            asm volatile("s_waitcnt vmcnt(0)" ::: "memory");
        }
        __builtin_amdgcn_sched_barrier(0);
        __builtin_amdgcn_s_barrier();
        asm volatile("" ::: "memory");

        #pragma unroll
        for (int t2 = 0; t2 < 2; ++t2) {
            const unsigned short* kbuf = (const unsigned short*)(smemB + KOFF(cur) + t2 * 8192);
            const unsigned short* vbuf = (const unsigned short*)(smemB + VOFF(cur) + t2 * 8192);
            const float* pcb = (const float*)(smemB + POFF(cur) + t2 * 1024);

            f32x4 st[4];
            #pragma unroll
            for (int f = 0; f < 4; ++f) st[f] = (f32x4){0.f, 0.f, 0.f, 0.f};
            __builtin_amdgcn_s_setprio(1);
            #pragma unroll
            for (int ec = 0; ec < 2; ++ec) {
                int pos = (4 * ec + g) ^ (m16 & 7);
                #pragma unroll
                for (int f = 0; f < 4; ++f) {
                    bf16x8 ka = *(bf16x8*)&kbuf[(16 * f + m16) * 64 + pos * 8];
                    st[f] = __builtin_amdgcn_mfma_f32_16x16x32_bf16(ka, qf[ec], st[f], 0, 0, 0);
                }
            }
            __builtin_amdgcn_s_setprio(0);

            float psum = 0.f;
            float ps_[16], pg_[16];
            #pragma unroll
            for (int f = 0; f < 4; ++f) {
                #pragma unroll
                for (int r = 0; r < 4; ++r) {
                    float4 pc4 = *(const float4*)&pcb[(16 * f + 4 * g + r) * 4];
                    float p = exp2f(st[f][r]);
                    psum += p;
                    float d = psiq - pc4.x;
                    float cd = fmaf(cq, pc4.y, sq * pc4.z);
                    float arg = fmaf(-d, d, fmaf(wgt, cd, nwgt));  // w*cd - w - d^2
                    float pgv = exp2f(arg);
                    spgl += pgv;
                    ps_[f * 4 + r] = p;
                    pg_[f * 4 + r] = pgv;
                }
            }
            ssel += psum;

            union PK8 { unsigned w[8]; bf16x8 v[2]; } SS, GG;
            #pragma unroll
            for (int i2 = 0; i2 < 8; ++i2) {
                __hip_bfloat162 hs = __float22bfloat162_rn(
                    make_float2(ps_[2 * i2], ps_[2 * i2 + 1]));
                __hip_bfloat162 hg = __float22bfloat162_rn(
                    make_float2(pg_[2 * i2], pg_[2 * i2 + 1]));
                unsigned ws2, wg2;
                __builtin_memcpy(&ws2, &hs, 4);
                __builtin_memcpy(&wg2, &hg, 4);
                SS.w[i2] = ws2;
                GG.w[i2] = wg2;
            }

            __builtin_amdgcn_s_setprio(1);
            #pragma unroll
            for (int c = 0; c < 2; ++c) {
                #pragma unroll
                for (int ef = 0; ef < 4; ++ef) {
                    bf16x8 vb = *(bf16x8*)&vbuf[(((ef * 2 + c) * 4 + g) * 16 + m16) * 8];
                    accS[ef] = __builtin_amdgcn_mfma_f32_16x16x32_bf16(SS.v[c], vb, accS[ef], 0, 0, 0);
                    accP[ef] = __builtin_amdgcn_mfma_f32_16x16x32_bf16(GG.v[c], vb, accP[ef], 0, 0, 0);
                }
            }
            __builtin_amdgcn_s_setprio(0);
        }

        asm volatile("" ::: "memory");
        __builtin_amdgcn_s_barrier();
        cur ^= 1;
    }

    ssel += __shfl_xor(ssel, 16); ssel += __shfl_xor(ssel, 32);
    spgl += __shfl_xor(spgl, 16); spgl += __shfl_xor(spgl, 32);
    float cs = 0.9f / ssel;
    float cp = 0.1f / (spgl + 1e-6f);
    float* ob = out + ((size_t)(b * LL + l0 + wv * 16) * CC + (size_t)h * EE);
    #pragma unroll
    for (int r = 0; r < 4; ++r) {
        float csr = __shfl(cs, 4 * g + r);
        float cpr = __shfl(cp, 4 * g + r);
        #pragma unroll
        for (int f = 0; f < 4; ++f) {
            ob[(size_t)(4 * g + r) * CC + 16 * f + m16] =
                csr * accS[f][r] + cpr * accP[f][r];
        }
    }
#undef KOFF
#undef VOFF
#undef POFF
#undef STAGE
}

extern "C" void kernel_launch(void* const* d_in, const int* in_sizes, int n_in,
                              void* d_out, int out_size, void* d_ws, size_t ws_size,
                              hipStream_t stream) {
    const float* q = (const float*)d_in[0];
    const float* k = (const float*)d_in[1];
    const float* v = (const float*)d_in[2];
    // d_in[3] = sigma (unused by the reference)
    const float* hurst = (const float*)d_in[4];
    const float* tau = (const float*)d_in[5];
    float* out = (float*)d_out;

    float* ws = (float*)d_ws;
    float* psi    = ws;                            // 32768
    float* taut   = psi + 32768;                   // 32768
    float* part_s = taut + 32768;                  // 32768 (8 octants)
    float* part_c = part_s + 32768;                // 32768
    float* pcs    = part_c + 32768;                // 131072
    unsigned short* Qp = (unsigned short*)(pcs + 131072);
    unsigned short* Kp = Qp + (size_t)2097152;
    unsigned short* Vp = Kp + (size_t)2097152;
    unsigned short* Agh = Vp + (size_t)2097152;
    unsigned short* Agl = Agh + (size_t)1048576;
    unsigned short* Xh  = (unsigned short*)d_out;  // X lives in d_out (8MB fit,
    unsigned short* Xl  = Xh + (size_t)2097152;    // fully overwritten by k_attn)

    k_pre1<<<672, 1024, 0, stream>>>(hurst, tau, q, k, v, psi, taut,
                                     Agh, Agl, Xh, Xl, Qp, Kp, Vp);
    k_hilb<<<512, 256, 0, stream>>>(q, Agh, Agl, Xh, Xl, part_s, part_c);
    k_pcs<<<32, 1024, 0, stream>>>(psi, taut, part_s, part_c, pcs);
    k_attn<<<BB * HH * (LL / 64), 256, 0, stream>>>(Qp, Kp, Vp, pcs, out);
}